// Round 3
// baseline (299.851 us; speedup 1.0000x reference)
//
#include <hip/hip_runtime.h>

// BertFusion: out = softmax(H @ V^T) @ V    B=8, L=2048, V=1024, D=1024, fp32.
//
// Fast path (needs 64 MB d_ws):
//   P01: H fp32 -> Hh fp16 (ws) ; V fp32 -> Vh fp16 + VTh fp16 (one kernel)
//   G1:  S = Hh @ Vh^T   (fp32 -> d_out)
//   K2:  softmax rows of S -> fp16 P in ws (reuses Hh; dead after G1)
//   G2:  O = P @ VTh^T   (fp32 -> d_out)
// Slow path (ws too small): round-2 kernels (proven).
//
// gemm256 v3: tile 256x128, BK=32, 512 thr (8 waves 4Mx2N, wave-tile 64x64),
// 3 LDS buffers (72 KB) -> 2 blocks/CU co-resident (grid 512 = 2x256):
// cross-block overlap absorbs barrier/lgkm/vmcnt stalls (m114). Per K-tile:
// 8 ds_read_b128 + 3 global_load_lds (stage t+2 into buf (t+2)%3, which was
// sealed by tile t-1's closing barrier) + 16 MFMA. Counted vmcnt(3) at tile
// end (t+1 guaranteed landed, t+2 stays in flight, ~2 K-tiles of slack).
// Sync idiom = m201 template: raw s_barrier builtin + explicit
// s_waitcnt lgkmcnt(0) + sched_barrier(0) + setprio around MFMA cluster.
// XCD-chunked bijective swizzle: batch b <-> XCD b (B-panel 2MB L2-resident).

typedef _Float16 half8_t __attribute__((ext_vector_type(8)));
typedef _Float16 half4_t __attribute__((ext_vector_type(4)));
typedef __fp16   fp16x2  __attribute__((ext_vector_type(2)));
typedef float    f32x4   __attribute__((ext_vector_type(4)));

#define B_ 8
#define L_ 2048
#define V_ 1024
#define D_ 1024

__device__ __forceinline__ half8_t cvt8(f32x4 a, f32x4 b) {
  union { half8_t h; fp16x2 p[4]; } u;
  u.p[0] = __builtin_amdgcn_cvt_pkrtz(a[0], a[1]);
  u.p[1] = __builtin_amdgcn_cvt_pkrtz(a[2], a[3]);
  u.p[2] = __builtin_amdgcn_cvt_pkrtz(b[0], b[1]);
  u.p[3] = __builtin_amdgcn_cvt_pkrtz(b[2], b[3]);
  return u.h;
}
__device__ __forceinline__ half4_t cvt4(f32x4 a) {
  union { half4_t h; fp16x2 p[2]; } u;
  u.p[0] = __builtin_amdgcn_cvt_pkrtz(a[0], a[1]);
  u.p[1] = __builtin_amdgcn_cvt_pkrtz(a[2], a[3]);
  return u.h;
}

__device__ __forceinline__ void gload_lds16(const _Float16* g, _Float16* l) {
  __builtin_amdgcn_global_load_lds(
      (const __attribute__((address_space(1))) unsigned int*)(g),
      (__attribute__((address_space(3))) unsigned int*)(l), 16, 0, 0);
}

// ---------------- P01: merged preprocessing -------------------------------
// blocks [0, 8192):  H fp32 -> Hh fp16   (2048 el/block)
// blocks [8192,10240): V fp32 -> Vh fp16 + VTh fp16 (64x64 tile/block)
__global__ __launch_bounds__(256) void p01_conv(const float* __restrict__ H,
                                                _Float16* __restrict__ Hh,
                                                const float* __restrict__ V,
                                                _Float16* __restrict__ Vh,
                                                _Float16* __restrict__ VTh) {
  const int t = threadIdx.x;
  if (blockIdx.x < 8192) {
    const size_t i = ((size_t)blockIdx.x * 256 + t) * 8;  // 8 el/thread
    f32x4 a = *(const f32x4*)(H + i);
    f32x4 b = *(const f32x4*)(H + i + 4);
    *(half8_t*)(Hh + i) = cvt8(a, b);
    return;
  }
  const int lin = blockIdx.x - 8192;        // [0, 2048)
  const int b   = lin >> 8;                 // 0..7
  const int d0  = (lin & 15) * 64;
  const int v0  = ((lin >> 4) & 15) * 64;
  const float* Vb = V + (size_t)b * V_ * D_;
  __shared__ __align__(16) _Float16 Lt[64 * 80];
  const int dc4 = (t & 15) * 4;
  #pragma unroll
  for (int it = 0; it < 4; ++it) {
    const int vr = (t >> 4) + it * 16;
    f32x4 x = *(const f32x4*)(Vb + (size_t)(v0 + vr) * D_ + d0 + dc4);
    half4_t h = cvt4(x);
    *(half4_t*)(Vh + (size_t)b * V_ * D_ + (size_t)(v0 + vr) * D_ + d0 + dc4) = h;
    #pragma unroll
    for (int j = 0; j < 4; ++j) Lt[(dc4 + j) * 80 + vr] = h[j];
  }
  __syncthreads();
  #pragma unroll
  for (int it = 0; it < 2; ++it) {
    const int dr = (t >> 3) + it * 32;
    const int vc = (t & 7) * 8;
    half8_t y = *(const half8_t*)&Lt[dr * 80 + vc];
    *(half8_t*)(VTh + (size_t)b * D_ * V_ + (size_t)(d0 + dr) * V_ + v0 + vc) = y;
  }
}

// ---------------- gemm256 v3: 256x128 tile, 2 blocks/CU -------------------
// Fixed geometry (G1 and G2): per batch M=2048, N=1024, K=1024;
// lda=ldb=ldc=1024; batch strides A,C = 2048*1024, B = 1024*1024.
// C[m][n] = sum_k A[m][k] * B[n][k], fp32 out. Grid = 512.
__global__ __launch_bounds__(512, 4) void gemm256(
    const _Float16* __restrict__ A, const _Float16* __restrict__ B,
    float* __restrict__ C) {
  // XCD-chunked bijective swizzle (512 blocks, 64 per XCD = one batch each).
  int lin = blockIdx.x;
  lin = (lin & 7) * 64 + (lin >> 3);
  const int bz  = lin >> 6;         // batch == XCD
  const int rem = lin & 63;
  const int my  = rem >> 3;         // 0..7  m-tile (256 rows)
  const int nx  = rem & 7;          // 0..7  n-tile (128 cols)
  const int m0 = my * 256, n0 = nx * 128;

  const _Float16* Ap = A + (size_t)bz * (2048 * 1024) + (size_t)m0 * 1024;
  const _Float16* Bp = B + (size_t)bz * (1024 * 1024) + (size_t)n0 * 1024;
  float*          Cp = C + (size_t)bz * (2048 * 1024);

  // 3 buffers; per buffer A: [kg 0..3][row 0..255][8 halves] = 16 KB,
  //                       B: [kg 0..3][row 0..127][8 halves] =  8 KB.
  __shared__ __align__(16) _Float16 As[3][8192];
  __shared__ __align__(16) _Float16 Bs[3][4096];

  const int t    = threadIdx.x;
  const int lane = t & 63;
  const int wid  = t >> 6;
  const int wm   = wid >> 1;   // 0..3 (rows wm*64 .. +63)
  const int wn   = wid & 1;    // 0..1 (cols wn*64 .. +63)
  const int fr   = lane & 15;
  const int fk   = lane >> 4;  // 0..3 (k-chunk fk*8 .. +7)

  f32x4 acc[4][4];
  {
    f32x4 z = {0.f, 0.f, 0.f, 0.f};
    #pragma unroll
    for (int i = 0; i < 4; ++i)
      #pragma unroll
      for (int j = 0; j < 4; ++j) acc[i][j] = z;
  }

  // Stage one K-tile (A 16 KB = 2 sweeps, B 8 KB = 1 sweep), 16B/thread each.
  // LDS dest linear in sweep cell -> per-wave contiguous (HW requirement).
  #define STGA(BUFL, KTT)                                                      \
    {                                                                          \
      _Pragma("unroll")                                                        \
      for (int i_ = 0; i_ < 2; ++i_) {                                         \
        const int c_ = i_ * 512 + t;                                           \
        const int kg_ = c_ >> 8, r_ = c_ & 255;                                \
        gload_lds16(Ap + (size_t)r_ * 1024 + (KTT) * 32 + kg_ * 8,             \
                    &As[BUFL][c_ * 8]);                                        \
      }                                                                        \
    }
  #define STGB(BUFL, KTT)                                                      \
    {                                                                          \
      const int kg_ = t >> 7, r_ = t & 127;                                    \
      gload_lds16(Bp + (size_t)r_ * 1024 + (KTT) * 32 + kg_ * 8,               \
                  &Bs[BUFL][t * 8]);                                           \
    }

  // One K-tile. Reads buf (KT)%3; stages KT+2 into buf (KT+2)%3, which was
  // sealed by TILE(KT-1)'s closing barrier (its reads were consumed by that
  // tile's MFMA before the barrier). vmcnt(3) leaves only KT+2's 3 loads in
  // flight -> KT+1's staging (issued 2 tiles ago) is guaranteed landed.
  #define TILE(KT, BUFL, BUFS)                                                 \
    {                                                                          \
      half8_t a[4], b[4];                                                      \
      _Pragma("unroll")                                                        \
      for (int mt = 0; mt < 4; ++mt)                                           \
        a[mt] = *(const half8_t*)&As[BUFL][(fk * 256 + wm * 64 + mt * 16 + fr) * 8]; \
      _Pragma("unroll")                                                        \
      for (int nt = 0; nt < 4; ++nt)                                           \
        b[nt] = *(const half8_t*)&Bs[BUFL][(fk * 128 + wn * 64 + nt * 16 + fr) * 8]; \
      if ((KT) < 30) { STGA(BUFS, (KT) + 2) STGB(BUFS, (KT) + 2) }             \
      __builtin_amdgcn_s_barrier();                                            \
      asm volatile("s_waitcnt lgkmcnt(0)" ::: "memory");                       \
      __builtin_amdgcn_sched_barrier(0);                                       \
      __builtin_amdgcn_s_setprio(1);                                           \
      _Pragma("unroll")                                                        \
      for (int nt = 0; nt < 4; ++nt)                                           \
        _Pragma("unroll")                                                      \
        for (int mt = 0; mt < 4; ++mt)                                         \
          acc[mt][nt] = __builtin_amdgcn_mfma_f32_16x16x32_f16(                \
              a[mt], b[nt], acc[mt][nt], 0, 0, 0);                             \
      __builtin_amdgcn_s_setprio(0);                                           \
      if ((KT) <= 29) {                                                        \
        asm volatile("s_waitcnt vmcnt(3)" ::: "memory");                       \
      } else if ((KT) == 30) {                                                 \
        asm volatile("s_waitcnt vmcnt(0)" ::: "memory");                       \
      }                                                                        \
      __builtin_amdgcn_s_barrier();                                            \
    }

  // Prologue: stage K-tiles 0 (buf0) and 1 (buf1); vmcnt(3) -> tile 0 landed.
  STGA(0, 0) STGB(0, 0) STGA(1, 1) STGB(1, 1)
  asm volatile("s_waitcnt vmcnt(3)" ::: "memory");
  __builtin_amdgcn_s_barrier();

  #pragma unroll 1
  for (int ktp = 0; ktp < 10; ++ktp) {
    const int k3 = ktp * 3;
    TILE(k3, 0, 2)
    TILE(k3 + 1, 1, 0)
    TILE(k3 + 2, 2, 1)
  }
  TILE(30, 0, 2)
  TILE(31, 1, 0)
  #undef TILE
  #undef STGA
  #undef STGB

  // C/D layout: col = lane&15, row = (lane>>4)*4 + reg   [m89/m91]
  const int rq = (lane >> 4) * 4;
  const int cb = n0 + wn * 64 + (lane & 15);
  const int rb = m0 + wm * 64 + rq;
  #pragma unroll
  for (int mt = 0; mt < 4; ++mt)
    #pragma unroll
    for (int nt = 0; nt < 4; ++nt) {
      #pragma unroll
      for (int r = 0; r < 4; ++r)
        Cp[(size_t)(rb + mt * 16 + r) * 1024 + cb + nt * 16] = acc[mt][nt][r];
    }
}

// ---------------- K2: softmax, one wave per row, no barriers --------------
__global__ __launch_bounds__(256) void k2_softmax(const float* __restrict__ S,
                                                  _Float16* __restrict__ P) {
  const int t    = threadIdx.x;
  const int lane = t & 63;
  const int row  = blockIdx.x * 4 + (t >> 6);
  const float* Sr = S + (size_t)row * V_;

  f32x4 s[4];
  #pragma unroll
  for (int j = 0; j < 4; ++j) s[j] = *(const f32x4*)(Sr + (lane + 64 * j) * 4);

  float m = -1e30f;
  #pragma unroll
  for (int j = 0; j < 4; ++j)
    m = fmaxf(m, fmaxf(fmaxf(s[j][0], s[j][1]), fmaxf(s[j][2], s[j][3])));
  #pragma unroll
  for (int off = 1; off < 64; off <<= 1) m = fmaxf(m, __shfl_xor(m, off, 64));

  float sum = 0.f;
  #pragma unroll
  for (int j = 0; j < 4; ++j) {
    s[j][0] = __expf(s[j][0] - m); s[j][1] = __expf(s[j][1] - m);
    s[j][2] = __expf(s[j][2] - m); s[j][3] = __expf(s[j][3] - m);
    sum += (s[j][0] + s[j][1]) + (s[j][2] + s[j][3]);
  }
  #pragma unroll
  for (int off = 1; off < 64; off <<= 1) sum += __shfl_xor(sum, off, 64);
  const float inv = 1.0f / sum;

  _Float16* Pr = P + (size_t)row * V_;
  #pragma unroll
  for (int j = 0; j < 4; ++j) {
    f32x4 e = {s[j][0] * inv, s[j][1] * inv, s[j][2] * inv, s[j][3] * inv};
    *(half4_t*)(Pr + (lane + 64 * j) * 4) = cvt4(e);
  }
}

// ================= slow fallback (round-2, proven) =================
__global__ __launch_bounds__(256, 2) void k1_slow(
    const float* __restrict__ H, const float* __restrict__ Vv, float* __restrict__ S) {
  const int b  = blockIdx.z;
  const int m0 = blockIdx.y * 128;
  const int n0 = blockIdx.x * 128;
  const float* Hb = H  + (size_t)b * L_ * D_;
  const float* Vb = Vv + (size_t)b * V_ * D_;
  float*       Sb = S  + (size_t)b * L_ * V_;
  __shared__ __align__(16) _Float16 As[2][4096];
  __shared__ __align__(16) _Float16 Bs[2][4096];
  const int t = threadIdx.x, lane = t & 63, wm = (t >> 6) >> 1, wn = (t >> 6) & 1;
  f32x4 acc[4][4];
  { f32x4 z = {0,0,0,0};
    #pragma unroll
    for (int i = 0; i < 4; ++i)
      #pragma unroll
      for (int j = 0; j < 4; ++j) acc[i][j] = z; }
  const int skg = t & 3, sm = t >> 2;
  for (int kt = 0; kt < 32; ++kt) {
    const int kbase = kt * 32 + skg * 8, buf = kt & 1;
    #pragma unroll
    for (int h = 0; h < 2; ++h) {
      const int m = sm + h * 64;
      const float* sa = Hb + (size_t)(m0 + m) * D_ + kbase;
      const float* sb = Vb + (size_t)(n0 + m) * D_ + kbase;
      const int cell = skg * 128 + (m ^ (skg * 2));
      *(half8_t*)&As[buf][cell * 8] = cvt8(*(const f32x4*)sa, *(const f32x4*)(sa + 4));
      *(half8_t*)&Bs[buf][cell * 8] = cvt8(*(const f32x4*)sb, *(const f32x4*)(sb + 4));
    }
    __syncthreads();
    const int fkg = lane >> 4, fr = lane & 15;
    half8_t af[4];
    #pragma unroll
    for (int mt = 0; mt < 4; ++mt)
      af[mt] = *(const half8_t*)&As[buf][(fkg * 128 + ((wm * 64 + mt * 16 + fr) ^ (fkg * 2))) * 8];
    #pragma unroll
    for (int nt = 0; nt < 4; ++nt) {
      half8_t bf = *(const half8_t*)&Bs[buf][(fkg * 128 + ((wn * 64 + nt * 16 + fr) ^ (fkg * 2))) * 8];
      #pragma unroll
      for (int mt = 0; mt < 4; ++mt)
        acc[mt][nt] = __builtin_amdgcn_mfma_f32_16x16x32_f16(af[mt], bf, acc[mt][nt], 0, 0, 0);
    }
  }
  const int rq = (lane >> 4) * 4;
  #pragma unroll
  for (int mt = 0; mt < 4; ++mt)
    #pragma unroll
    for (int nt = 0; nt < 4; ++nt) {
      const int col = n0 + wn * 64 + nt * 16 + (lane & 15);
      const int rb  = m0 + wm * 64 + mt * 16 + rq;
      #pragma unroll
      for (int r = 0; r < 4; ++r) Sb[(size_t)(rb + r) * V_ + col] = acc[mt][nt][r];
    }
}

__global__ __launch_bounds__(256) void k2_slow(float* __restrict__ S) {
  const int row = blockIdx.x;
  float* Sr = S + (size_t)row * V_;
  const int t = threadIdx.x;
  f32x4 s = ((const f32x4*)Sr)[t];
  float m = fmaxf(fmaxf(s[0], s[1]), fmaxf(s[2], s[3]));
  #pragma unroll
  for (int off = 1; off < 64; off <<= 1) m = fmaxf(m, __shfl_xor(m, off, 64));
  __shared__ float redm[4];
  __shared__ float reds[4];
  const int w = t >> 6;
  if ((t & 63) == 0) redm[w] = m;
  __syncthreads();
  m = fmaxf(fmaxf(redm[0], redm[1]), fmaxf(redm[2], redm[3]));
  const float e0 = __expf(s[0] - m), e1 = __expf(s[1] - m);
  const float e2 = __expf(s[2] - m), e3 = __expf(s[3] - m);
  float sum = (e0 + e1) + (e2 + e3);
  #pragma unroll
  for (int off = 1; off < 64; off <<= 1) sum += __shfl_xor(sum, off, 64);
  if ((t & 63) == 0) reds[w] = sum;
  __syncthreads();
  const float inv = 1.0f / ((reds[0] + reds[1]) + (reds[2] + reds[3]));
  half4_t p;
  p[0] = (_Float16)(e0 * inv); p[1] = (_Float16)(e1 * inv);
  p[2] = (_Float16)(e2 * inv); p[3] = (_Float16)(e3 * inv);
  *(half4_t*)((_Float16*)Sr + 4 * t) = p;
}

__global__ __launch_bounds__(512, 2) void k3_slow(
    const float* __restrict__ Vv, float* __restrict__ O) {
  const int b = blockIdx.y, r0 = blockIdx.x * 64;
  const float* Vb = Vv + (size_t)b * V_ * D_;
  float*       Ob = O  + (size_t)b * L_ * D_;
  const _Float16* Pb = (const _Float16*)Ob;
  __shared__ __align__(16) _Float16 Bs[32768];
  const int t = threadIdx.x, lane = t & 63, w = t >> 6;
  f32x4 acc[4][8];
  { f32x4 z = {0,0,0,0};
    #pragma unroll
    for (int i = 0; i < 4; ++i)
      #pragma unroll
      for (int j = 0; j < 8; ++j) acc[i][j] = z; }
  for (int kt = 0; kt < 32; ++kt) {
    const int v0 = kt * 32;
    #pragma unroll
    for (int i = 0; i < 8; ++i) {
      const int c = t + i * 512, kg = c >> 10, d = c & 1023;
      const float* src = Vb + (size_t)(v0 + kg * 8) * D_ + d;
      f32x4 x0, x1;
      x0[0] = src[0*D_]; x0[1] = src[1*D_]; x0[2] = src[2*D_]; x0[3] = src[3*D_];
      x1[0] = src[4*D_]; x1[1] = src[5*D_]; x1[2] = src[6*D_]; x1[3] = src[7*D_];
      *(half8_t*)&Bs[(kg * 1024 + d) * 8] = cvt8(x0, x1);
    }
    __syncthreads();
    const int fkg = lane >> 4, fr = lane & 15;
    half8_t af[4];
    #pragma unroll
    for (int mt = 0; mt < 4; ++mt)
      af[mt] = *(const half8_t*)(Pb + (size_t)(r0 + mt * 16 + fr) * 2048 + v0 + fkg * 8);
    #pragma unroll
    for (int nt = 0; nt < 8; ++nt) {
      half8_t bf = *(const half8_t*)&Bs[(fkg * 1024 + w * 128 + nt * 16 + fr) * 8];
      #pragma unroll
      for (int mt = 0; mt < 4; ++mt)
        acc[mt][nt] = __builtin_amdgcn_mfma_f32_16x16x32_f16(af[mt], bf, acc[mt][nt], 0, 0, 0);
    }
    __syncthreads();
  }
  const int rq = (lane >> 4) * 4;
  #pragma unroll
  for (int mt = 0; mt < 4; ++mt)
    #pragma unroll
    for (int nt = 0; nt < 8; ++nt) {
      const int col = w * 128 + nt * 16 + (lane & 15);
      const int rb  = r0 + mt * 16 + rq;
      #pragma unroll
      for (int r = 0; r < 4; ++r) Ob[(size_t)(rb + r) * D_ + col] = acc[mt][nt][r];
    }
}

extern "C" void kernel_launch(void* const* d_in, const int* in_sizes, int n_in,
                              void* d_out, int out_size, void* d_ws, size_t ws_size,
                              hipStream_t stream) {
  (void)in_sizes; (void)n_in; (void)out_size;
  const float* H  = (const float*)d_in[0];   // (8, 2048, 1024)
  const float* Vv = (const float*)d_in[1];   // (8, 1024, 1024)
  float* O = (float*)d_out;                  // (8, 2048, 1024)

  const size_t need = (size_t)64 * 1024 * 1024;  // Hh/P 32M + Vh 16M + VTh 16M
  if (ws_size >= need && d_ws != nullptr) {
    _Float16* Hh  = (_Float16*)d_ws;            // 32 MB; becomes P after G1
    _Float16* Vh  = Hh + (size_t)B_ * L_ * D_;  // 16 MB
    _Float16* VTh = Vh + (size_t)B_ * V_ * D_;  // 16 MB
    _Float16* P   = Hh;                         // reuse (Hh dead after G1)

    p01_conv<<<dim3(8192 + 2048), 256, 0, stream>>>(H, Hh, Vv, Vh, VTh);
    // S = Hh @ Vh^T  -> d_out
    gemm256<<<dim3(512), 512, 0, stream>>>(Hh, Vh, O);
    // P = softmax(S) -> ws (fp16, dense); 1 wave/row
    k2_softmax<<<dim3(B_ * L_ / 4), 256, 0, stream>>>(O, P);
    // O = P @ VTh^T  -> d_out (A,B both in ws: no aliasing with C)
    gemm256<<<dim3(512), 512, 0, stream>>>(P, VTh, O);
  } else {
    k1_slow<<<dim3(V_ / 128, L_ / 128, B_), 256, 0, stream>>>(H, Vv, O);
    k2_slow<<<dim3(B_ * L_), 256, 0, stream>>>(O);
    k3_slow<<<dim3(L_ / 64, B_), 512, 0, stream>>>(Vv, O);
  }
}

// Round 4
// 284.428 us; speedup vs baseline: 1.0542x; 1.0542x over previous
//
#include <hip/hip_runtime.h>

// BertFusion: out = softmax(H @ V^T) @ V    B=8, L=2048, V=1024, D=1024, fp32.
//
// Fast path (needs 64 MB d_ws):
//   P01: H fp32 -> Hh fp16 (ws) ; V fp32 -> Vh fp16 + VTh fp16 (one kernel)
//   G1:  S = Hh @ Vh^T   (fp32 -> d_out)
//   K2:  softmax rows of S -> fp16 P in ws (reuses Hh; dead after G1)
//   G2:  O = P @ VTh^T   (fp32 -> d_out)
// Slow path (ws too small): round-2 kernels (proven).
//
// gemm256 v4 = round-2 v2 (proven 56.4us) + fragment READ-AHEAD + coalesced
// epilogue. 256x256 tile, BK=64, 512 thr (8 waves 2Mx4N), 2 LDS buffers,
// 4 phases/K-tile, ONE barrier per phase. Phase p issues ds_reads for phase
// p+1's MFMA quadrant, then MFMAs the current quadrant (sched_barrier(0)
// pins issue order) -> each wave's own MFMA cluster hides its LDS latency.
// Staging slots (t+2): B0@P2, B1@P3, A0+A1@P4 (region-lifetime checked).
// Boundary vmcnt(4) at end-P3 (t+1's 8 loads older than newest 4 -> retired)
// so P4 pre-reads tile t+1's aLo/b0 fragments from the other buffer.
// b0 fragments parity-double-buffered with STATIC names (rule #20).
// Epilogue: per-wave 16KB LDS transpose -> dwordx4 stores (256B segments).

typedef _Float16 half8_t __attribute__((ext_vector_type(8)));
typedef _Float16 half4_t __attribute__((ext_vector_type(4)));
typedef __fp16   fp16x2  __attribute__((ext_vector_type(2)));
typedef float    f32x4   __attribute__((ext_vector_type(4)));

#define B_ 8
#define L_ 2048
#define V_ 1024
#define D_ 1024

__device__ __forceinline__ half8_t cvt8(f32x4 a, f32x4 b) {
  union { half8_t h; fp16x2 p[4]; } u;
  u.p[0] = __builtin_amdgcn_cvt_pkrtz(a[0], a[1]);
  u.p[1] = __builtin_amdgcn_cvt_pkrtz(a[2], a[3]);
  u.p[2] = __builtin_amdgcn_cvt_pkrtz(b[0], b[1]);
  u.p[3] = __builtin_amdgcn_cvt_pkrtz(b[2], b[3]);
  return u.h;
}
__device__ __forceinline__ half4_t cvt4(f32x4 a) {
  union { half4_t h; fp16x2 p[2]; } u;
  u.p[0] = __builtin_amdgcn_cvt_pkrtz(a[0], a[1]);
  u.p[1] = __builtin_amdgcn_cvt_pkrtz(a[2], a[3]);
  return u.h;
}

__device__ __forceinline__ void gload_lds16(const _Float16* g, _Float16* l) {
  __builtin_amdgcn_global_load_lds(
      (const __attribute__((address_space(1))) unsigned int*)(g),
      (__attribute__((address_space(3))) unsigned int*)(l), 16, 0, 0);
}

// ---------------- P01: merged preprocessing -------------------------------
// blocks [0, 8192):  H fp32 -> Hh fp16   (2048 el/block)
// blocks [8192,10240): V fp32 -> Vh fp16 + VTh fp16 (64x64 tile/block)
__global__ __launch_bounds__(256) void p01_conv(const float* __restrict__ H,
                                                _Float16* __restrict__ Hh,
                                                const float* __restrict__ V,
                                                _Float16* __restrict__ Vh,
                                                _Float16* __restrict__ VTh) {
  const int t = threadIdx.x;
  if (blockIdx.x < 8192) {
    const size_t i = ((size_t)blockIdx.x * 256 + t) * 8;  // 8 el/thread
    f32x4 a = *(const f32x4*)(H + i);
    f32x4 b = *(const f32x4*)(H + i + 4);
    *(half8_t*)(Hh + i) = cvt8(a, b);
    return;
  }
  const int lin = blockIdx.x - 8192;        // [0, 2048)
  const int b   = lin >> 8;                 // 0..7
  const int d0  = (lin & 15) * 64;
  const int v0  = ((lin >> 4) & 15) * 64;
  const float* Vb = V + (size_t)b * V_ * D_;
  __shared__ __align__(16) _Float16 Lt[64 * 80];
  const int dc4 = (t & 15) * 4;
  #pragma unroll
  for (int it = 0; it < 4; ++it) {
    const int vr = (t >> 4) + it * 16;
    f32x4 x = *(const f32x4*)(Vb + (size_t)(v0 + vr) * D_ + d0 + dc4);
    half4_t h = cvt4(x);
    *(half4_t*)(Vh + (size_t)b * V_ * D_ + (size_t)(v0 + vr) * D_ + d0 + dc4) = h;
    #pragma unroll
    for (int j = 0; j < 4; ++j) Lt[(dc4 + j) * 80 + vr] = h[j];
  }
  __syncthreads();
  #pragma unroll
  for (int it = 0; it < 2; ++it) {
    const int dr = (t >> 3) + it * 32;
    const int vc = (t & 7) * 8;
    half8_t y = *(const half8_t*)&Lt[dr * 80 + vc];
    *(half8_t*)(VTh + (size_t)b * D_ * V_ + (size_t)(d0 + dr) * V_ + v0 + vc) = y;
  }
}

// ---------------- gemm256 v4: 256^2, read-ahead pipelined -----------------
// Fixed geometry (G1 and G2): per batch M=2048, N=1024, K=1024;
// lda=ldb=ldc=1024; batch strides A,C = 2048*1024, B = 1024*1024.
// C[m][n] = sum_k A[m][k] * B[n][k], fp32 out. Grid = 256.
__global__ __launch_bounds__(512, 2) void gemm256(
    const _Float16* __restrict__ A, const _Float16* __restrict__ B,
    float* __restrict__ C) {
  // XCD-chunked bijective swizzle (grid = 256, 256 % 8 == 0).
  int lin = blockIdx.x;
  lin = (lin & 7) * 32 + (lin >> 3);
  const int bz = lin >> 5;          // batch
  const int my = (lin >> 2) & 7;    // m-block (consecutive share A panel)
  const int nx = lin & 3;           // n-block
  const int m0 = my * 256, n0 = nx * 256;

  const _Float16* Ap = A + (size_t)bz * (2048 * 1024) + (size_t)m0 * 1024;
  const _Float16* Bp = B + (size_t)bz * (1024 * 1024) + (size_t)n0 * 1024;
  float*          Cp = C + (size_t)bz * (2048 * 1024);

  // [kgg 0..7][row 0..255][8 halves] per buffer; 32 KB per matrix per buffer.
  __shared__ __align__(16) _Float16 As[2][16384];
  __shared__ __align__(16) _Float16 Bs[2][16384];

  const int t    = threadIdx.x;
  const int lane = t & 63;
  const int wid  = t >> 6;
  const int wm   = wid >> 2;   // 0..1  (rows wm*128 .. +127)
  const int wn   = wid & 3;    // 0..3  (cols wn*64 .. +63)
  const int fr   = lane & 15;
  const int fk   = lane >> 4;  // 0..3

  f32x4 acc[8][4];
  {
    f32x4 z = {0.f, 0.f, 0.f, 0.f};
    #pragma unroll
    for (int i = 0; i < 8; ++i)
      #pragma unroll
      for (int j = 0; j < 4; ++j) acc[i][j] = z;
  }

  // stage one half-tile (128 rows x 64 k): 2 x global_load_lds(16B)/thread.
  #define STG(PTR, ARR, BUFL, H, KTT)                                          \
    {                                                                          \
      _Pragma("unroll")                                                        \
      for (int i_ = 0; i_ < 2; ++i_) {                                         \
        const int c_ = i_ * 512 + t;                                           \
        const int kg_ = c_ >> 7, r_ = c_ & 127;                                \
        gload_lds16(PTR + (size_t)((H) * 128 + r_) * 1024 + (KTT) * 64 + kg_ * 8, \
                    &ARR[BUFL][(kg_ * 256 + (H) * 128 + r_) * 8]);             \
      }                                                                        \
    }

  #define LDA(BUFL, mt_, ks_) \
    (*(const half8_t*)&As[BUFL][(((ks_) * 4 + fk) * 256 + wm * 128 + (mt_) * 16 + fr) * 8])
  #define LDB(BUFL, nt_, ks_) \
    (*(const half8_t*)&Bs[BUFL][(((ks_) * 4 + fk) * 256 + wn * 64 + (nt_) * 16 + fr) * 8])

  #define MFMA16(AF, BF, MOFF, NOFF)                                           \
    __builtin_amdgcn_s_setprio(1);                                             \
    _Pragma("unroll")                                                          \
    for (int ks = 0; ks < 2; ++ks)                                             \
      _Pragma("unroll")                                                        \
      for (int nt = 0; nt < 2; ++nt)                                           \
        _Pragma("unroll")                                                      \
        for (int mt = 0; mt < 4; ++mt)                                         \
          acc[(MOFF) + mt][(NOFF) + nt] =                                      \
              __builtin_amdgcn_mfma_f32_16x16x32_f16(                          \
                  AF[mt][ks], BF[nt][ks], acc[(MOFF) + mt][(NOFF) + nt], 0, 0, 0); \
    __builtin_amdgcn_s_setprio(0);

  half8_t aLo[4][2], aHi[4][2], b1[2][2], b0A[2][2], b0B[2][2];

  // One K-tile. Fragments for q00 (aLo, b0cur) were read in the PREVIOUS
  // tile's P4. Each phase issues the next quadrant's ds_reads (and this
  // tile's staging of t+2) before its MFMA; sched_barrier(0) pins the order.
  // Region lifetimes (reads COMPLETE in the phase of their consuming MFMA,
  // sealed by that phase's single end-barrier):
  //   b0 region: completes P1 -> STG B0(t+2) @P2.  b1: P2 -> B1(t+2) @P3.
  //   A  region: aLo P1, aHi P3 -> A0+A1(t+2) @P4.
  // vmcnt(4) at end-P3: newest 4 = B0,B1(t+2) -> all of t+1 retired, so P4
  // may pre-read tile t+1's aLo/b0 from the other buffer.
  #define TILE(KT, BUFL, OTH, B0C, B0N)                                        \
    {                                                                          \
      /* P1: issue b1 reads; MFMA q00(aLo, b0cur) */                           \
      _Pragma("unroll")                                                        \
      for (int ks = 0; ks < 2; ++ks)                                           \
        _Pragma("unroll")                                                      \
        for (int nt = 0; nt < 2; ++nt) b1[nt][ks] = LDB(BUFL, 2 + nt, ks);     \
      __builtin_amdgcn_sched_barrier(0);                                       \
      MFMA16(aLo, B0C, 0, 0)                                                   \
      __builtin_amdgcn_s_barrier();                                            \
      /* P2: issue aHi reads; STG B0(t+2); MFMA q01(aLo, b1) */                \
      _Pragma("unroll")                                                        \
      for (int ks = 0; ks < 2; ++ks)                                           \
        _Pragma("unroll")                                                      \
        for (int mt = 0; mt < 4; ++mt) aHi[mt][ks] = LDA(BUFL, 4 + mt, ks);    \
      if ((KT) < 14) { STG(Bp, Bs, BUFL, 0, (KT) + 2) }                        \
      __builtin_amdgcn_sched_barrier(0);                                       \
      MFMA16(aLo, b1, 0, 2)                                                    \
      __builtin_amdgcn_s_barrier();                                            \
      /* P3: STG B1(t+2); MFMA q11(aHi, b1); boundary vmcnt */                 \
      if ((KT) < 14) { STG(Bp, Bs, BUFL, 1, (KT) + 2) }                        \
      __builtin_amdgcn_sched_barrier(0);                                       \
      MFMA16(aHi, b1, 4, 2)                                                    \
      if ((KT) == 14) {                                                        \
        asm volatile("s_waitcnt vmcnt(0)" ::: "memory");                       \
      } else if ((KT) < 14) {                                                  \
        asm volatile("s_waitcnt vmcnt(4)" ::: "memory");                       \
      }                                                                        \
      __builtin_amdgcn_s_barrier();                                            \
      /* P4: pre-read t+1's aLo/b0 from OTH; STG A0,A1(t+2); MFMA q10 */       \
      if ((KT) < 15) {                                                         \
        _Pragma("unroll")                                                      \
        for (int ks = 0; ks < 2; ++ks) {                                       \
          _Pragma("unroll")                                                    \
          for (int mt = 0; mt < 4; ++mt) aLo[mt][ks] = LDA(OTH, mt, ks);       \
          _Pragma("unroll")                                                    \
          for (int nt = 0; nt < 2; ++nt) B0N[nt][ks] = LDB(OTH, nt, ks);       \
        }                                                                      \
      }                                                                        \
      if ((KT) < 14) { STG(Ap, As, BUFL, 0, (KT) + 2) STG(Ap, As, BUFL, 1, (KT) + 2) } \
      __builtin_amdgcn_sched_barrier(0);                                       \
      MFMA16(aHi, B0C, 4, 0)                                                   \
      __builtin_amdgcn_s_barrier();                                            \
    }

  // Prologue: stage K-tiles 0 and 1; vmcnt(8) -> tile 0 landed; pre-read
  // tile 0's aLo/b0 fragments.
  STG(Bp, Bs, 0, 0, 0) STG(Ap, As, 0, 0, 0) STG(Bp, Bs, 0, 1, 0) STG(Ap, As, 0, 1, 0)
  STG(Bp, Bs, 1, 0, 1) STG(Ap, As, 1, 0, 1) STG(Bp, Bs, 1, 1, 1) STG(Ap, As, 1, 1, 1)
  asm volatile("s_waitcnt vmcnt(8)" ::: "memory");
  __builtin_amdgcn_s_barrier();
  #pragma unroll
  for (int ks = 0; ks < 2; ++ks) {
    #pragma unroll
    for (int mt = 0; mt < 4; ++mt) aLo[mt][ks] = LDA(0, mt, ks);
    #pragma unroll
    for (int nt = 0; nt < 2; ++nt) b0A[nt][ks] = LDB(0, nt, ks);
  }

  #pragma unroll 1
  for (int tp = 0; tp < 8; ++tp) {
    const int kt = tp * 2;
    TILE(kt, 0, 1, b0A, b0B)
    TILE(kt + 1, 1, 0, b0B, b0A)
  }
  #undef TILE
  #undef STG
  #undef LDA
  #undef LDB
  #undef MFMA16

  // ---- Epilogue: coalesced C-store via per-wave 16KB LDS transpose.
  // C/D layout: col = lane&15, row = (lane>>4)*4 + reg   [m89/m91]
  const int rq = (lane >> 4) * 4;
  float* reg = (wid < 4) ? ((float*)As + wid * 4096)
                         : ((float*)Bs + (wid - 4) * 4096);
  #pragma unroll
  for (int h = 0; h < 2; ++h) {
    __syncthreads();
    #pragma unroll
    for (int mt = 0; mt < 4; ++mt)
      #pragma unroll
      for (int nt = 0; nt < 4; ++nt)
        #pragma unroll
        for (int r = 0; r < 4; ++r)
          reg[(mt * 16 + rq + r) * 64 + nt * 16 + fr] = acc[h * 4 + mt][nt][r];
    __syncthreads();
    #pragma unroll
    for (int rr = 0; rr < 16; ++rr) {
      f32x4 v = *(const f32x4*)&reg[(rr * 4 + fk) * 64 + fr * 4];
      const int row = m0 + wm * 128 + h * 64 + rr * 4 + fk;
      *(f32x4*)&Cp[(size_t)row * 1024 + n0 + wn * 64 + fr * 4] = v;
    }
  }
}

// ---------------- K2: softmax, one wave per row, no barriers --------------
__global__ __launch_bounds__(256) void k2_softmax(const float* __restrict__ S,
                                                  _Float16* __restrict__ P) {
  const int t    = threadIdx.x;
  const int lane = t & 63;
  const int row  = blockIdx.x * 4 + (t >> 6);
  const float* Sr = S + (size_t)row * V_;

  f32x4 s[4];
  #pragma unroll
  for (int j = 0; j < 4; ++j) s[j] = *(const f32x4*)(Sr + (lane + 64 * j) * 4);

  float m = -1e30f;
  #pragma unroll
  for (int j = 0; j < 4; ++j)
    m = fmaxf(m, fmaxf(fmaxf(s[j][0], s[j][1]), fmaxf(s[j][2], s[j][3])));
  #pragma unroll
  for (int off = 1; off < 64; off <<= 1) m = fmaxf(m, __shfl_xor(m, off, 64));

  float sum = 0.f;
  #pragma unroll
  for (int j = 0; j < 4; ++j) {
    s[j][0] = __expf(s[j][0] - m); s[j][1] = __expf(s[j][1] - m);
    s[j][2] = __expf(s[j][2] - m); s[j][3] = __expf(s[j][3] - m);
    sum += (s[j][0] + s[j][1]) + (s[j][2] + s[j][3]);
  }
  #pragma unroll
  for (int off = 1; off < 64; off <<= 1) sum += __shfl_xor(sum, off, 64);
  const float inv = 1.0f / sum;

  _Float16* Pr = P + (size_t)row * V_;
  #pragma unroll
  for (int j = 0; j < 4; ++j) {
    f32x4 e = {s[j][0] * inv, s[j][1] * inv, s[j][2] * inv, s[j][3] * inv};
    *(half4_t*)(Pr + (lane + 64 * j) * 4) = cvt4(e);
  }
}

// ================= slow fallback (round-2, proven) =================
__global__ __launch_bounds__(256, 2) void k1_slow(
    const float* __restrict__ H, const float* __restrict__ Vv, float* __restrict__ S) {
  const int b  = blockIdx.z;
  const int m0 = blockIdx.y * 128;
  const int n0 = blockIdx.x * 128;
  const float* Hb = H  + (size_t)b * L_ * D_;
  const float* Vb = Vv + (size_t)b * V_ * D_;
  float*       Sb = S  + (size_t)b * L_ * V_;
  __shared__ __align__(16) _Float16 As[2][4096];
  __shared__ __align__(16) _Float16 Bs[2][4096];
  const int t = threadIdx.x, lane = t & 63, wm = (t >> 6) >> 1, wn = (t >> 6) & 1;
  f32x4 acc[4][4];
  { f32x4 z = {0,0,0,0};
    #pragma unroll
    for (int i = 0; i < 4; ++i)
      #pragma unroll
      for (int j = 0; j < 4; ++j) acc[i][j] = z; }
  const int skg = t & 3, sm = t >> 2;
  for (int kt = 0; kt < 32; ++kt) {
    const int kbase = kt * 32 + skg * 8, buf = kt & 1;
    #pragma unroll
    for (int h = 0; h < 2; ++h) {
      const int m = sm + h * 64;
      const float* sa = Hb + (size_t)(m0 + m) * D_ + kbase;
      const float* sb = Vb + (size_t)(n0 + m) * D_ + kbase;
      const int cell = skg * 128 + (m ^ (skg * 2));
      *(half8_t*)&As[buf][cell * 8] = cvt8(*(const f32x4*)sa, *(const f32x4*)(sa + 4));
      *(half8_t*)&Bs[buf][cell * 8] = cvt8(*(const f32x4*)sb, *(const f32x4*)(sb + 4));
    }
    __syncthreads();
    const int fkg = lane >> 4, fr = lane & 15;
    half8_t af[4];
    #pragma unroll
    for (int mt = 0; mt < 4; ++mt)
      af[mt] = *(const half8_t*)&As[buf][(fkg * 128 + ((wm * 64 + mt * 16 + fr) ^ (fkg * 2))) * 8];
    #pragma unroll
    for (int nt = 0; nt < 4; ++nt) {
      half8_t bf = *(const half8_t*)&Bs[buf][(fkg * 128 + ((wn * 64 + nt * 16 + fr) ^ (fkg * 2))) * 8];
      #pragma unroll
      for (int mt = 0; mt < 4; ++mt)
        acc[mt][nt] = __builtin_amdgcn_mfma_f32_16x16x32_f16(af[mt], bf, acc[mt][nt], 0, 0, 0);
    }
  }
  const int rq = (lane >> 4) * 4;
  #pragma unroll
  for (int mt = 0; mt < 4; ++mt)
    #pragma unroll
    for (int nt = 0; nt < 4; ++nt) {
      const int col = n0 + wn * 64 + nt * 16 + (lane & 15);
      const int rb  = m0 + wm * 64 + mt * 16 + rq;
      #pragma unroll
      for (int r = 0; r < 4; ++r) Sb[(size_t)(rb + r) * V_ + col] = acc[mt][nt][r];
    }
}

__global__ __launch_bounds__(256) void k2_slow(float* __restrict__ S) {
  const int row = blockIdx.x;
  float* Sr = S + (size_t)row * V_;
  const int t = threadIdx.x;
  f32x4 s = ((const f32x4*)Sr)[t];
  float m = fmaxf(fmaxf(s[0], s[1]), fmaxf(s[2], s[3]));
  #pragma unroll
  for (int off = 1; off < 64; off <<= 1) m = fmaxf(m, __shfl_xor(m, off, 64));
  __shared__ float redm[4];
  __shared__ float reds[4];
  const int w = t >> 6;
  if ((t & 63) == 0) redm[w] = m;
  __syncthreads();
  m = fmaxf(fmaxf(redm[0], redm[1]), fmaxf(redm[2], redm[3]));
  const float e0 = __expf(s[0] - m), e1 = __expf(s[1] - m);
  const float e2 = __expf(s[2] - m), e3 = __expf(s[3] - m);
  float sum = (e0 + e1) + (e2 + e3);
  #pragma unroll
  for (int off = 1; off < 64; off <<= 1) sum += __shfl_xor(sum, off, 64);
  if ((t & 63) == 0) reds[w] = sum;
  __syncthreads();
  const float inv = 1.0f / ((reds[0] + reds[1]) + (reds[2] + reds[3]));
  half4_t p;
  p[0] = (_Float16)(e0 * inv); p[1] = (_Float16)(e1 * inv);
  p[2] = (_Float16)(e2 * inv); p[3] = (_Float16)(e3 * inv);
  *(half4_t*)((_Float16*)Sr + 4 * t) = p;
}

__global__ __launch_bounds__(512, 2) void k3_slow(
    const float* __restrict__ Vv, float* __restrict__ O) {
  const int b = blockIdx.y, r0 = blockIdx.x * 64;
  const float* Vb = Vv + (size_t)b * V_ * D_;
  float*       Ob = O  + (size_t)b * L_ * D_;
  const _Float16* Pb = (const _Float16*)Ob;
  __shared__ __align__(16) _Float16 Bs[32768];
  const int t = threadIdx.x, lane = t & 63, w = t >> 6;
  f32x4 acc[4][8];
  { f32x4 z = {0,0,0,0};
    #pragma unroll
    for (int i = 0; i < 4; ++i)
      #pragma unroll
      for (int j = 0; j < 8; ++j) acc[i][j] = z; }
  for (int kt = 0; kt < 32; ++kt) {
    const int v0 = kt * 32;
    #pragma unroll
    for (int i = 0; i < 8; ++i) {
      const int c = t + i * 512, kg = c >> 10, d = c & 1023;
      const float* src = Vb + (size_t)(v0 + kg * 8) * D_ + d;
      f32x4 x0, x1;
      x0[0] = src[0*D_]; x0[1] = src[1*D_]; x0[2] = src[2*D_]; x0[3] = src[3*D_];
      x1[0] = src[4*D_]; x1[1] = src[5*D_]; x1[2] = src[6*D_]; x1[3] = src[7*D_];
      *(half8_t*)&Bs[(kg * 1024 + d) * 8] = cvt8(x0, x1);
    }
    __syncthreads();
    const int fkg = lane >> 4, fr = lane & 15;
    half8_t af[4];
    #pragma unroll
    for (int mt = 0; mt < 4; ++mt)
      af[mt] = *(const half8_t*)(Pb + (size_t)(r0 + mt * 16 + fr) * 2048 + v0 + fkg * 8);
    #pragma unroll
    for (int nt = 0; nt < 8; ++nt) {
      half8_t bf = *(const half8_t*)&Bs[(fkg * 1024 + w * 128 + nt * 16 + fr) * 8];
      #pragma unroll
      for (int mt = 0; mt < 4; ++mt)
        acc[mt][nt] = __builtin_amdgcn_mfma_f32_16x16x32_f16(af[mt], bf, acc[mt][nt], 0, 0, 0);
    }
    __syncthreads();
  }
  const int rq = (lane >> 4) * 4;
  #pragma unroll
  for (int mt = 0; mt < 4; ++mt)
    #pragma unroll
    for (int nt = 0; nt < 8; ++nt) {
      const int col = w * 128 + nt * 16 + (lane & 15);
      const int rb  = r0 + mt * 16 + rq;
      #pragma unroll
      for (int r = 0; r < 4; ++r) Ob[(size_t)(rb + r) * D_ + col] = acc[mt][nt][r];
    }
}

extern "C" void kernel_launch(void* const* d_in, const int* in_sizes, int n_in,
                              void* d_out, int out_size, void* d_ws, size_t ws_size,
                              hipStream_t stream) {
  (void)in_sizes; (void)n_in; (void)out_size;
  const float* H  = (const float*)d_in[0];   // (8, 2048, 1024)
  const float* Vv = (const float*)d_in[1];   // (8, 1024, 1024)
  float* O = (float*)d_out;                  // (8, 2048, 1024)

  const size_t need = (size_t)64 * 1024 * 1024;  // Hh/P 32M + Vh 16M + VTh 16M
  if (ws_size >= need && d_ws != nullptr) {
    _Float16* Hh  = (_Float16*)d_ws;            // 32 MB; becomes P after G1
    _Float16* Vh  = Hh + (size_t)B_ * L_ * D_;  // 16 MB
    _Float16* VTh = Vh + (size_t)B_ * V_ * D_;  // 16 MB
    _Float16* P   = Hh;                         // reuse (Hh dead after G1)

    p01_conv<<<dim3(8192 + 2048), 256, 0, stream>>>(H, Hh, Vv, Vh, VTh);
    // S = Hh @ Vh^T  -> d_out
    gemm256<<<dim3(256), 512, 0, stream>>>(Hh, Vh, O);
    // P = softmax(S) -> ws (fp16, dense); 1 wave/row
    k2_softmax<<<dim3(B_ * L_ / 4), 256, 0, stream>>>(O, P);
    // O = P @ VTh^T  -> d_out (A,B both in ws: no aliasing with C)
    gemm256<<<dim3(256), 512, 0, stream>>>(P, VTh, O);
  } else {
    k1_slow<<<dim3(V_ / 128, L_ / 128, B_), 256, 0, stream>>>(H, Vv, O);
    k2_slow<<<dim3(B_ * L_), 256, 0, stream>>>(O);
    k3_slow<<<dim3(L_ / 64, B_), 512, 0, stream>>>(Vv, O);
  }
}